// Round 2
// baseline (1569.059 us; speedup 1.0000x reference)
//
#include <hip/hip_runtime.h>
#include <hip/hip_bf16.h>
#include <cstdint>

// Problem constants
#define BB 64
#define SS 1024
#define DCn 64
#define Hn 128
#define G3 384

__device__ __forceinline__ float sigmoid_f(float x) {
  return 1.0f / (1.0f + __expf(-x));
}
__device__ __forceinline__ float tanh_f(float x) {
  float xc = fminf(fmaxf(x, -15.0f), 15.0f);
  float t = __expf(-2.0f * xc);
  return (1.0f - t) / (1.0f + t);
}

// ---------------- Phase A: embeddings + conditional concat -> inter, concept
__global__ __launch_bounds__(256) void embed_kernel(
    const int* __restrict__ qseq, const int* __restrict__ cseq,
    const int* __restrict__ q2c, const int* __restrict__ q2cm,
    const float* __restrict__ cemb, const float* __restrict__ remb,
    float* __restrict__ inter, float* __restrict__ concept) {
  int pos = blockIdx.x * 2 + (threadIdx.x >> 7);   // [0, 65536)
  int d = threadIdx.x & 127;
  int q = qseq[pos];
  int corr = cseq[pos];
  float val;
  if (d < 64) {
    float acc = 0.f, msum = 0.f;
#pragma unroll
    for (int c = 0; c < 4; ++c) {
      int id = q2c[q * 4 + c];
      float m = (float)q2cm[q * 4 + c];
      acc += m * cemb[id * 64 + d];
      msum += m;
    }
    val = acc / fmaxf(msum, 1.0f);
    concept[(size_t)pos * 64 + d] = val;
  } else {
    val = remb[corr * 64 + (d - 64)];
  }
  // corr==1: [concept|corr]  else [corr|concept]
  int slot = (corr == 1) ? d : ((d < 64) ? d + 64 : d - 64);
  inter[(size_t)pos * 128 + slot] = val;
}

// ---------------- Generic f32 GEMM: C[M,N] = A[M,128] * Bm[N,128]^T + bias[N]
// 64x64 tile, 256 threads, 4x4 per thread. XOR-swizzled float4 LDS (conflict-free).
__global__ __launch_bounds__(256) void gemm_bt_kernel(
    const float* __restrict__ A, const float* __restrict__ Bm,
    const float* __restrict__ bias, float* __restrict__ C, int N) {
  __shared__ float4 As4[64][32];
  __shared__ float4 Bs4[64][32];
  const int m0 = blockIdx.x * 64;
  const int n0 = blockIdx.y * 64;
  const int tid = threadIdx.x;
  const float4* Ag = (const float4*)(A) + (size_t)m0 * 32;
  const float4* Bg = (const float4*)(Bm) + (size_t)n0 * 32;
#pragma unroll
  for (int l = 0; l < 8; ++l) {
    int idx = tid + l * 256;        // 0..2047
    int r = idx >> 5, k4 = idx & 31;
    int c = k4 ^ ((r >> 2) & 7);
    As4[r][c] = Ag[(size_t)r * 32 + k4];
    Bs4[r][c] = Bg[(size_t)r * 32 + k4];
  }
  __syncthreads();
  const int t16 = tid >> 4;  // 0..15 (row group)
  const int tn = tid & 15;   // 0..15 (col group)
  float acc[4][4] = {};
#pragma unroll
  for (int k4 = 0; k4 < 32; ++k4) {
    float4 a[4], b[4];
    int ca = k4 ^ (t16 & 7);
    int cb = k4 ^ (tn & 7);
#pragma unroll
    for (int i = 0; i < 4; ++i) a[i] = As4[t16 * 4 + i][ca];
#pragma unroll
    for (int j = 0; j < 4; ++j) b[j] = Bs4[tn * 4 + j][cb];
#pragma unroll
    for (int i = 0; i < 4; ++i)
#pragma unroll
      for (int j = 0; j < 4; ++j)
        acc[i][j] += a[i].x * b[j].x + a[i].y * b[j].y +
                     a[i].z * b[j].z + a[i].w * b[j].w;
  }
  float4 bv;
  bv.x = bias[n0 + tn * 4 + 0];
  bv.y = bias[n0 + tn * 4 + 1];
  bv.z = bias[n0 + tn * 4 + 2];
  bv.w = bias[n0 + tn * 4 + 3];
#pragma unroll
  for (int i = 0; i < 4; ++i) {
    float4 o;
    o.x = acc[i][0] + bv.x;
    o.y = acc[i][1] + bv.y;
    o.z = acc[i][2] + bv.z;
    o.w = acc[i][3] + bv.w;
    *(float4*)&C[(size_t)(m0 + t16 * 4 + i) * N + n0 + tn * 4] = o;
  }
}

// ---------------- Phase C: GRU recurrence. 1 block per batch, 768 threads.
// Thread (g, half): W_hh[g, half*64 .. half*64+63] in 64 VGPRs.
// Pair partial dots combine via __shfl_xor(.,1); h broadcast via LDS.
__global__ __launch_bounds__(768, 3) void gru_kernel(
    const float* __restrict__ Xp, const float* __restrict__ W_hh,
    const float* __restrict__ b_hh, float* __restrict__ rnn_out) {
  const int b = blockIdx.x;
  const int tid = threadIdx.x;     // 0..767
  const int g = tid >> 1;          // 0..383 (output row)
  const int half = tid & 1;        // k-slice: [0,64) or [64,128)
  __shared__ float hbuf[128];
  __shared__ float zbuf[128];
  __shared__ float gnbuf[128];
  __shared__ float inbuf[128];

  float4 w4[16];
  const float4* Wrow = (const float4*)(W_hh + (size_t)g * 128 + half * 64);
#pragma unroll
  for (int i = 0; i < 16; ++i) w4[i] = Wrow[i];
  const float bh = b_hh[g];
  float h_old = 0.0f;
  if (tid < 128) hbuf[tid] = 0.0f;
  __syncthreads();

  const float* xp_ptr = Xp + (size_t)b * SS * G3 + g;
  float* rout = rnn_out + (size_t)b * SS * Hn;
  // depth-2 prefetch of the streaming Xp rows
  float xp0 = xp_ptr[0];
  float xp1 = xp_ptr[G3];
  const int j = g & 127;

  for (int t = 0; t < SS; ++t) {
    float xp2 = (t < SS - 2) ? xp_ptr[(size_t)(t + 2) * G3] : 0.0f;
    // partial dot: W_hh[g, half-slice] . h[half-slice]
    const float4* h4 = (const float4*)(hbuf + half * 64);
    float a0 = 0.f, a1 = 0.f, a2 = 0.f, a3 = 0.f;
#pragma unroll
    for (int i = 0; i < 16; i += 4) {
      float4 h0 = h4[i], h1 = h4[i + 1], h2 = h4[i + 2], h3 = h4[i + 3];
      a0 += w4[i].x     * h0.x + w4[i].y     * h0.y + w4[i].z     * h0.z + w4[i].w     * h0.w;
      a1 += w4[i + 1].x * h1.x + w4[i + 1].y * h1.y + w4[i + 1].z * h1.z + w4[i + 1].w * h1.w;
      a2 += w4[i + 2].x * h2.x + w4[i + 2].y * h2.y + w4[i + 2].z * h2.z + w4[i + 2].w * h2.w;
      a3 += w4[i + 3].x * h3.x + w4[i + 3].y * h3.y + w4[i + 3].z * h3.z + w4[i + 3].w * h3.w;
    }
    float acc = (a0 + a1) + (a2 + a3);
    float total = acc + __shfl_xor(acc, 1) + bh;   // full gh[g] (+bias)
    if (half == 0) {
      if (g >= 256) {             // n-gate rows: publish gh_n and i_n
        gnbuf[j] = total;
        inbuf[j] = xp0;
      } else if (g >= 128) {      // z fully computable here
        zbuf[j] = sigmoid_f(xp0 + total);
      }
    }
    __syncthreads();
    if (half == 0 && g < 128) {
      float r = sigmoid_f(xp0 + total);
      float n = tanh_f(inbuf[j] + r * gnbuf[j]);
      float z = zbuf[j];
      float hn = (1.0f - z) * n + z * h_old;
      h_old = hn;
      rout[(size_t)t * Hn + j] = hn;
      hbuf[j] = hn;
    }
    xp0 = xp1;
    xp1 = xp2;
    __syncthreads();
  }
}

// ---------------- Phase D2: s[pos] = sum_a tanh(tmpA[pos,a]) * sim_w[a]
__global__ __launch_bounds__(256) void score_kernel(
    const float* __restrict__ tmpA, const float* __restrict__ sim_w,
    float* __restrict__ s) {
  int pos = blockIdx.x * 4 + (threadIdx.x >> 6);
  int lane = threadIdx.x & 63;
  const float* row = tmpA + (size_t)pos * 128;
  float v = tanh_f(row[lane]) * sim_w[lane] +
            tanh_f(row[lane + 64]) * sim_w[lane + 64];
#pragma unroll
  for (int o = 32; o; o >>= 1) v += __shfl_down(v, o);
  if (lane == 0) s[pos] = v;
}

// ---------------- Phase E: cumulative softmax-average + exclusive cumsum -> excl
__global__ __launch_bounds__(128) void attn_kernel(
    const float* __restrict__ s, const float* __restrict__ rnn,
    float* __restrict__ excl) {
  const int b = blockIdx.x;
  const int h = threadIdx.x;      // 0..127
  __shared__ float elds[SS];
  __shared__ float red[2];
  const float* sb = s + (size_t)b * SS;
  float m = -1e30f;
  for (int i = h; i < SS; i += 128) m = fmaxf(m, sb[i]);
#pragma unroll
  for (int o = 32; o; o >>= 1) m = fmaxf(m, __shfl_down(m, o));
  if ((h & 63) == 0) red[h >> 6] = m;
  __syncthreads();
  m = fmaxf(red[0], red[1]);
  for (int i = h; i < SS; i += 128) elds[i] = __expf(sb[i] - m);
  __syncthreads();

  const float* rb = rnn + (size_t)b * SS * Hn;
  float* eb = excl + (size_t)b * SS * Hn;
  float num = 0.f, den = 0.f, run = 0.f;
  float rcur = rb[h];
  for (int t = 0; t < SS; ++t) {
    float rnxt = (t < SS - 1) ? rb[(size_t)(t + 1) * Hn + h] : 0.0f;
    float e = elds[t];
    den += e;
    num += e * rcur;
    eb[(size_t)t * Hn + h] = run;                    // exclusive
    run += num * __builtin_amdgcn_rcpf(den);         // attn_t
    rcur = rnxt;
  }
}

// ---------------- Phase F: logits -> sigmoid. One wave per (b, t).
__global__ __launch_bounds__(256) void out_kernel(
    const float* __restrict__ excl, const float* __restrict__ rnn,
    const float* __restrict__ concept, const float* __restrict__ pred_w,
    const float* __restrict__ pred_b, float* __restrict__ out) {
  int idx = blockIdx.x * 4 + (threadIdx.x >> 6);    // [0, 64*1023)
  int lane = threadIdx.x & 63;
  if (idx >= BB * (SS - 1)) return;
  int b = idx / (SS - 1), t = idx % (SS - 1);
  const float* e = excl + ((size_t)b * SS + t) * Hn;
  const float* r = rnn + ((size_t)b * SS + t) * Hn;
  const float* c = concept + ((size_t)b * SS + t + 1) * DCn;
  float v = e[lane] * pred_w[lane] + e[lane + 64] * pred_w[lane + 64] +
            r[lane] * pred_w[128 + lane] + r[lane + 64] * pred_w[192 + lane] +
            c[lane] * pred_w[256 + lane];
#pragma unroll
  for (int o = 32; o; o >>= 1) v += __shfl_down(v, o);
  if (lane == 0) out[idx] = sigmoid_f(v + pred_b[0]);
}

extern "C" void kernel_launch(void* const* d_in, const int* in_sizes, int n_in,
                              void* d_out, int out_size, void* d_ws, size_t ws_size,
                              hipStream_t stream) {
  const int* qseq = (const int*)d_in[0];
  const int* cseq = (const int*)d_in[1];
  const int* q2c = (const int*)d_in[2];
  const int* q2cm = (const int*)d_in[3];
  const float* cemb = (const float*)d_in[4];
  const float* remb = (const float*)d_in[5];
  const float* mlp_w = (const float*)d_in[6];
  const float* mlp_b = (const float*)d_in[7];
  const float* sim_w = (const float*)d_in[8];
  const float* W_ih = (const float*)d_in[9];
  const float* b_ih = (const float*)d_in[10];
  const float* W_hh = (const float*)d_in[11];
  const float* b_hh = (const float*)d_in[12];
  const float* pred_w = (const float*)d_in[13];
  const float* pred_b = (const float*)d_in[14];
  float* out = (float*)d_out;

  // workspace layout (f32 elements); total 46,137,344 floats = 176 MiB
  float* ws = (float*)d_ws;
  float* concept = ws;                 // 4,194,304  [B,S,64]   live A..F
  float* inter = ws + 4194304;         // 8,388,608  [B,S,128]  live A..B1
  float* Xp = ws + 12582912;           // 25,165,824 [B,S,384]  live B1..C
  float* rnn = ws + 37748736;          // 8,388,608  [B,S,128]  live C..F
  float* tmpA = inter;                 // alias (inter dead after B1)
  float* excl = Xp;                    // alias (Xp dead after C)
  float* sbuf = Xp + 8388608;          // alias, 256 KiB inside Xp region

  embed_kernel<<<32768, 256, 0, stream>>>(qseq, cseq, q2c, q2cm, cemb, remb,
                                          inter, concept);
  gemm_bt_kernel<<<dim3(1024, 6), 256, 0, stream>>>(inter, W_ih, b_ih, Xp, 384);
  gru_kernel<<<64, 768, 0, stream>>>(Xp, W_hh, b_hh, rnn);
  gemm_bt_kernel<<<dim3(1024, 2), 256, 0, stream>>>(rnn, mlp_w, mlp_b, tmpA, 128);
  score_kernel<<<16384, 256, 0, stream>>>(tmpA, sim_w, sbuf);
  attn_kernel<<<64, 128, 0, stream>>>(sbuf, rnn, excl);
  out_kernel<<<16368, 256, 0, stream>>>(excl, rnn, concept, pred_w, pred_b, out);
}

// Round 3
// 1260.268 us; speedup vs baseline: 1.2450x; 1.2450x over previous
//
#include <hip/hip_runtime.h>
#include <hip/hip_bf16.h>
#include <cstdint>

// Problem constants
#define BB 64
#define SS 1024
#define DCn 64
#define Hn 128
#define G3 384

__device__ __forceinline__ float sigmoid_f(float x) {
  return 1.0f / (1.0f + __expf(-x));
}
__device__ __forceinline__ float tanh_f(float x) {
  float xc = fminf(fmaxf(x, -15.0f), 15.0f);
  float t = __expf(-2.0f * xc);
  return (1.0f - t) / (1.0f + t);
}

// ---------------- Phase A: embeddings + conditional concat -> inter, concept
__global__ __launch_bounds__(256) void embed_kernel(
    const int* __restrict__ qseq, const int* __restrict__ cseq,
    const int* __restrict__ q2c, const int* __restrict__ q2cm,
    const float* __restrict__ cemb, const float* __restrict__ remb,
    float* __restrict__ inter, float* __restrict__ concept) {
  int pos = blockIdx.x * 2 + (threadIdx.x >> 7);   // [0, 65536)
  int d = threadIdx.x & 127;
  int q = qseq[pos];
  int corr = cseq[pos];
  float val;
  if (d < 64) {
    float acc = 0.f, msum = 0.f;
#pragma unroll
    for (int c = 0; c < 4; ++c) {
      int id = q2c[q * 4 + c];
      float m = (float)q2cm[q * 4 + c];
      acc += m * cemb[id * 64 + d];
      msum += m;
    }
    val = acc / fmaxf(msum, 1.0f);
    concept[(size_t)pos * 64 + d] = val;
  } else {
    val = remb[corr * 64 + (d - 64)];
  }
  // corr==1: [concept|corr]  else [corr|concept]
  int slot = (corr == 1) ? d : ((d < 64) ? d + 64 : d - 64);
  inter[(size_t)pos * 128 + slot] = val;
}

// ---------------- Generic f32 GEMM: C[M,N] = A[M,128] * Bm[N,128]^T + bias[N]
// 64x64 tile, 256 threads, 4x4 per thread. XOR-swizzled float4 LDS (conflict-free).
__global__ __launch_bounds__(256) void gemm_bt_kernel(
    const float* __restrict__ A, const float* __restrict__ Bm,
    const float* __restrict__ bias, float* __restrict__ C, int N) {
  __shared__ float4 As4[64][32];
  __shared__ float4 Bs4[64][32];
  const int m0 = blockIdx.x * 64;
  const int n0 = blockIdx.y * 64;
  const int tid = threadIdx.x;
  const float4* Ag = (const float4*)(A) + (size_t)m0 * 32;
  const float4* Bg = (const float4*)(Bm) + (size_t)n0 * 32;
#pragma unroll
  for (int l = 0; l < 8; ++l) {
    int idx = tid + l * 256;        // 0..2047
    int r = idx >> 5, k4 = idx & 31;
    int c = k4 ^ ((r >> 2) & 7);
    As4[r][c] = Ag[(size_t)r * 32 + k4];
    Bs4[r][c] = Bg[(size_t)r * 32 + k4];
  }
  __syncthreads();
  const int t16 = tid >> 4;  // 0..15 (row group)
  const int tn = tid & 15;   // 0..15 (col group)
  float acc[4][4] = {};
#pragma unroll
  for (int k4 = 0; k4 < 32; ++k4) {
    float4 a[4], b[4];
    int ca = k4 ^ (t16 & 7);
    int cb = k4 ^ (tn & 7);
#pragma unroll
    for (int i = 0; i < 4; ++i) a[i] = As4[t16 * 4 + i][ca];
#pragma unroll
    for (int j = 0; j < 4; ++j) b[j] = Bs4[tn * 4 + j][cb];
#pragma unroll
    for (int i = 0; i < 4; ++i)
#pragma unroll
      for (int j = 0; j < 4; ++j)
        acc[i][j] += a[i].x * b[j].x + a[i].y * b[j].y +
                     a[i].z * b[j].z + a[i].w * b[j].w;
  }
  float4 bv;
  bv.x = bias[n0 + tn * 4 + 0];
  bv.y = bias[n0 + tn * 4 + 1];
  bv.z = bias[n0 + tn * 4 + 2];
  bv.w = bias[n0 + tn * 4 + 3];
#pragma unroll
  for (int i = 0; i < 4; ++i) {
    float4 o;
    o.x = acc[i][0] + bv.x;
    o.y = acc[i][1] + bv.y;
    o.z = acc[i][2] + bv.z;
    o.w = acc[i][3] + bv.w;
    *(float4*)&C[(size_t)(m0 + t16 * 4 + i) * N + n0 + tn * 4] = o;
  }
}

// ---------------- Phase C: GRU recurrence. 1 block per batch, 768 threads.
// Thread (g, half) owns W_hh[g, half*64 .. +63] in 64 PINNED VGPRs (inline-asm
// opacity forbids rematerialization of the global loads inside the t-loop).
// h broadcast via LDS with a dual-copy layout: h[0..63] @ float 0,
// h[64..127] @ float 68 (byte 272 == 16 mod 128) so even lanes (half=0) hit
// banks {4i..4i+3} and odd lanes (half=1) hit {4i+4..4i+7}: conflict-free.
__global__ __launch_bounds__(768, 3) void gru_kernel(
    const float* __restrict__ Xp, const float* __restrict__ W_hh,
    const float* __restrict__ b_hh, float* __restrict__ rnn_out) {
  const int b = blockIdx.x;
  const int tid = threadIdx.x;     // 0..767
  const int g = tid >> 1;          // 0..383 (output row)
  const int half = tid & 1;        // k-slice: [0,64) or [64,128)
  __shared__ float hbuf[132];      // [0..63]=h[0..63], [68..131]=h[64..127]
  __shared__ float zbuf[128];
  __shared__ float gnbuf[128];
  __shared__ float inbuf[128];

  float w[64];
  {
    const float4* Wrow = (const float4*)(W_hh + (size_t)g * 128 + half * 64);
#pragma unroll
    for (int i = 0; i < 16; ++i) {
      float4 t4 = Wrow[i];
      w[4 * i + 0] = t4.x; w[4 * i + 1] = t4.y;
      w[4 * i + 2] = t4.z; w[4 * i + 3] = t4.w;
    }
  }
#pragma unroll
  for (int i = 0; i < 64; ++i) asm volatile("" : "+v"(w[i]));

  const float bh = b_hh[g];
  float h_old = 0.0f;
  if (tid < 128) hbuf[tid + ((tid >= 64) ? 4 : 0)] = 0.0f;
  __syncthreads();

  const float* xp_ptr = Xp + (size_t)b * SS * G3 + g;
  float* rout = rnn_out + (size_t)b * SS * Hn;
  // depth-2 prefetch of the streaming Xp rows
  float xp0 = xp_ptr[0];
  float xp1 = xp_ptr[G3];
  const int j = g & 127;
  const float4* h4 = (const float4*)(hbuf + half * 68);

  for (int t = 0; t < SS; ++t) {
    float xp2 = (t < SS - 2) ? xp_ptr[(size_t)(t + 2) * G3] : 0.0f;
    // partial dot: W_hh[g, half-slice] . h[half-slice]
    float a0 = 0.f, a1 = 0.f, a2 = 0.f, a3 = 0.f;
#pragma unroll
    for (int i = 0; i < 16; i += 4) {
      float4 h0 = h4[i], h1 = h4[i + 1], h2 = h4[i + 2], h3 = h4[i + 3];
      a0 += w[4*i+ 0] * h0.x + w[4*i+ 1] * h0.y + w[4*i+ 2] * h0.z + w[4*i+ 3] * h0.w;
      a1 += w[4*i+ 4] * h1.x + w[4*i+ 5] * h1.y + w[4*i+ 6] * h1.z + w[4*i+ 7] * h1.w;
      a2 += w[4*i+ 8] * h2.x + w[4*i+ 9] * h2.y + w[4*i+10] * h2.z + w[4*i+11] * h2.w;
      a3 += w[4*i+12] * h3.x + w[4*i+13] * h3.y + w[4*i+14] * h3.z + w[4*i+15] * h3.w;
    }
    float acc = (a0 + a1) + (a2 + a3);
    float total = acc + __shfl_xor(acc, 1) + bh;   // full gh[g] (+bias)
    float r_pre = 0.0f;
    if (half == 0) {
      if (g >= 256) {             // n-gate rows: publish gh_n and i_n
        gnbuf[j] = total;
        inbuf[j] = xp0;
      } else if (g >= 128) {      // z fully computable here
        zbuf[j] = sigmoid_f(xp0 + total);
      } else {                    // r computable pre-barrier (own dot only)
        r_pre = sigmoid_f(xp0 + total);
      }
    }
    __syncthreads();
    if (half == 0 && g < 128) {
      float n = tanh_f(inbuf[j] + r_pre * gnbuf[j]);
      float z = zbuf[j];
      float hn = (1.0f - z) * n + z * h_old;
      h_old = hn;
      hbuf[j + ((j >= 64) ? 4 : 0)] = hn;          // LDS first (critical path)
      rout[(size_t)t * Hn + j] = hn;               // global store off-path
    }
    xp0 = xp1;
    xp1 = xp2;
    __syncthreads();
  }
}

// ---------------- Phase D2: s[pos] = sum_a tanh(tmpA[pos,a]) * sim_w[a]
__global__ __launch_bounds__(256) void score_kernel(
    const float* __restrict__ tmpA, const float* __restrict__ sim_w,
    float* __restrict__ s) {
  int pos = blockIdx.x * 4 + (threadIdx.x >> 6);
  int lane = threadIdx.x & 63;
  const float* row = tmpA + (size_t)pos * 128;
  float v = tanh_f(row[lane]) * sim_w[lane] +
            tanh_f(row[lane + 64]) * sim_w[lane + 64];
#pragma unroll
  for (int o = 32; o; o >>= 1) v += __shfl_down(v, o);
  if (lane == 0) s[pos] = v;
}

// ---------------- Phase E: cumulative softmax-average + exclusive cumsum -> excl
__global__ __launch_bounds__(128) void attn_kernel(
    const float* __restrict__ s, const float* __restrict__ rnn,
    float* __restrict__ excl) {
  const int b = blockIdx.x;
  const int h = threadIdx.x;      // 0..127
  __shared__ float elds[SS];
  __shared__ float red[2];
  const float* sb = s + (size_t)b * SS;
  float m = -1e30f;
  for (int i = h; i < SS; i += 128) m = fmaxf(m, sb[i]);
#pragma unroll
  for (int o = 32; o; o >>= 1) m = fmaxf(m, __shfl_down(m, o));
  if ((h & 63) == 0) red[h >> 6] = m;
  __syncthreads();
  m = fmaxf(red[0], red[1]);
  for (int i = h; i < SS; i += 128) elds[i] = __expf(sb[i] - m);
  __syncthreads();

  const float* rb = rnn + (size_t)b * SS * Hn;
  float* eb = excl + (size_t)b * SS * Hn;
  float num = 0.f, den = 0.f, run = 0.f;
  float rcur = rb[h];
  for (int t = 0; t < SS; ++t) {
    float rnxt = (t < SS - 1) ? rb[(size_t)(t + 1) * Hn + h] : 0.0f;
    float e = elds[t];
    den += e;
    num += e * rcur;
    eb[(size_t)t * Hn + h] = run;                    // exclusive
    run += num * __builtin_amdgcn_rcpf(den);         // attn_t
    rcur = rnxt;
  }
}

// ---------------- Phase F: logits -> sigmoid. One wave per (b, t).
__global__ __launch_bounds__(256) void out_kernel(
    const float* __restrict__ excl, const float* __restrict__ rnn,
    const float* __restrict__ concept, const float* __restrict__ pred_w,
    const float* __restrict__ pred_b, float* __restrict__ out) {
  int idx = blockIdx.x * 4 + (threadIdx.x >> 6);    // [0, 64*1023)
  int lane = threadIdx.x & 63;
  if (idx >= BB * (SS - 1)) return;
  int b = idx / (SS - 1), t = idx % (SS - 1);
  const float* e = excl + ((size_t)b * SS + t) * Hn;
  const float* r = rnn + ((size_t)b * SS + t) * Hn;
  const float* c = concept + ((size_t)b * SS + t + 1) * DCn;
  float v = e[lane] * pred_w[lane] + e[lane + 64] * pred_w[lane + 64] +
            r[lane] * pred_w[128 + lane] + r[lane + 64] * pred_w[192 + lane] +
            c[lane] * pred_w[256 + lane];
#pragma unroll
  for (int o = 32; o; o >>= 1) v += __shfl_down(v, o);
  if (lane == 0) out[idx] = sigmoid_f(v + pred_b[0]);
}

extern "C" void kernel_launch(void* const* d_in, const int* in_sizes, int n_in,
                              void* d_out, int out_size, void* d_ws, size_t ws_size,
                              hipStream_t stream) {
  const int* qseq = (const int*)d_in[0];
  const int* cseq = (const int*)d_in[1];
  const int* q2c = (const int*)d_in[2];
  const int* q2cm = (const int*)d_in[3];
  const float* cemb = (const float*)d_in[4];
  const float* remb = (const float*)d_in[5];
  const float* mlp_w = (const float*)d_in[6];
  const float* mlp_b = (const float*)d_in[7];
  const float* sim_w = (const float*)d_in[8];
  const float* W_ih = (const float*)d_in[9];
  const float* b_ih = (const float*)d_in[10];
  const float* W_hh = (const float*)d_in[11];
  const float* b_hh = (const float*)d_in[12];
  const float* pred_w = (const float*)d_in[13];
  const float* pred_b = (const float*)d_in[14];
  float* out = (float*)d_out;

  // workspace layout (f32 elements); total 46,137,344 floats = 176 MiB
  float* ws = (float*)d_ws;
  float* concept = ws;                 // 4,194,304  [B,S,64]   live A..F
  float* inter = ws + 4194304;         // 8,388,608  [B,S,128]  live A..B1
  float* Xp = ws + 12582912;           // 25,165,824 [B,S,384]  live B1..C
  float* rnn = ws + 37748736;          // 8,388,608  [B,S,128]  live C..F
  float* tmpA = inter;                 // alias (inter dead after B1)
  float* excl = Xp;                    // alias (Xp dead after C)
  float* sbuf = Xp + 8388608;          // alias, 256 KiB inside Xp region

  embed_kernel<<<32768, 256, 0, stream>>>(qseq, cseq, q2c, q2cm, cemb, remb,
                                          inter, concept);
  gemm_bt_kernel<<<dim3(1024, 6), 256, 0, stream>>>(inter, W_ih, b_ih, Xp, 384);
  gru_kernel<<<64, 768, 0, stream>>>(Xp, W_hh, b_hh, rnn);
  gemm_bt_kernel<<<dim3(1024, 2), 256, 0, stream>>>(rnn, mlp_w, mlp_b, tmpA, 128);
  score_kernel<<<16384, 256, 0, stream>>>(tmpA, sim_w, sbuf);
  attn_kernel<<<64, 128, 0, stream>>>(sbuf, rnn, excl);
  out_kernel<<<16368, 256, 0, stream>>>(excl, rnn, concept, pred_w, pred_b, out);
}